// Round 2
// baseline (394.770 us; speedup 1.0000x reference)
//
#include <hip/hip_runtime.h>
#include <math.h>

#define WIDTH 512
#define HALF  256
#define DEPTH 32
#define BATCH 65536
#define RPW   4   // rows per wave

typedef float v2f __attribute__((ext_vector_type(2)));

// Precomputed per-(depth, physical position) parameters, duplicated into
// packed-pair form and stored in physical order [d][slot][lane] so the main
// kernel's loads are coalesced and need no broadcast movs.
//   physical p = lane*8 + slot ; entry q = (d*8+slot)*64 + lane
__device__ float4 g_AS[DEPTH * 8 * 64];  // {A, A, S, S}
__device__ float4 g_BC[DEPTH * 8 * 64];  // {-B, -B, cc, cc}
__device__ v2f    g_IK[DEPTH * 8 * 64];  // {ik, ik}

__global__ __launch_bounds__(256) void precompute_kernel(
    const float* __restrict__ thetas, const float* __restrict__ biases,
    const float* __restrict__ slopes1, const float* __restrict__ slopes2,
    const float* __restrict__ curvatures) {
  int tid = blockIdx.x * 256 + threadIdx.x;
  if (tid >= DEPTH * WIDTH) return;
  int d = tid >> 9;
  int p = tid & 511;
  // logical column of physical p AFTER layer d = rotl9(p, d+1)
  int rot = (d + 1) % 9;
  int j = ((p << rot) | (p >> (9 - rot))) & 511;
  int i = j >> 1;          // theta index
  int role = j & 1;        // 0 = n0 (x0*c + x1*s), 1 = n1 (-x0*s + x1*c)
  float th = thetas[d * HALF + i];
  float c = cosf(th), s = sinf(th);
  float m1 = expf(slopes1[d * WIDTH + j]);
  float m2 = expf(slopes2[d * WIDTH + j]);
  float a  = 0.5f * (m1 + m2);
  float cc = (m2 - m1) / (m1 + m2);   // (m2-m1)/(2a)
  float b  = sinhf(biases[d * WIDTH + j]);
  float ik = expf(-curvatures[d * WIDTH + j]);
  float A = a * c;
  float S = role ? (-a * s) : (a * s);
  int q = (d * 8 + (p & 7)) * 64 + (p >> 3);
  g_AS[q] = make_float4(A, A, S, S);
  g_BC[q] = make_float4(-b, -b, cc, cc);
  v2f v; v.x = ik; v.y = ik;
  g_IK[q] = v;
}

#if __has_builtin(__builtin_amdgcn_sqrtf)
#define FAST_SQRT(x) __builtin_amdgcn_sqrtf(x)
#else
#define FAST_SQRT(x) sqrtf(x)
#endif

__device__ __forceinline__ v2f vfma(v2f a, v2f b, v2f c) {
#if __has_builtin(__builtin_elementwise_fma)
  return __builtin_elementwise_fma(a, b, c);
#else
  v2f d;
  d.x = fmaf(a.x, b.x, c.x);
  d.y = fmaf(a.y, b.y, c.y);
  return d;
#endif
}

__device__ __forceinline__ v2f stepv(v2f xs, v2f v, v2f A, v2f S, v2f Bn,
                                     v2f C, v2f IK) {
  v2f u = vfma(xs, A, vfma(v, S, Bn));   // u = xs*A + v*S - B
  v2f t = vfma(u, u, IK);                // t = u*u + 1/k
  v2f q;
  q.x = FAST_SQRT(t.x);
  q.y = FAST_SQRT(t.y);
  return vfma(C, q, u);                  // u + cc*sqrt(t)
}

__device__ __forceinline__ v2f shflx(v2f x, int m) {
  v2f r;
  r.x = __shfl_xor(x.x, m, 64);
  r.y = __shfl_xor(x.y, m, 64);
  return r;
}

// K = physical bit this layer pairs on. K>=3: cross-lane (mask 1<<(K-3));
// K<3: intra-thread slot pair.
template <int K>
__device__ __forceinline__ void do_layer(int d, int lane, v2f (&x)[8][RPW / 2]) {
  const int base = d * 512 + lane;
  if constexpr (K >= 3) {
    const int m = 1 << (K - 3);
#pragma unroll
    for (int s = 0; s < 8; ++s) {
      float4 as = g_AS[base + s * 64];
      float4 bc = g_BC[base + s * 64];
      v2f ik = g_IK[base + s * 64];
      v2f A, S, Bn, C;
      A.x = as.x; A.y = as.y; S.x = as.z; S.y = as.w;
      Bn.x = bc.x; Bn.y = bc.y; C.x = bc.z; C.y = bc.w;
#pragma unroll
      for (int h = 0; h < RPW / 2; ++h) {
        v2f xs = x[s][h];
        v2f v = shflx(xs, m);
        x[s][h] = stepv(xs, v, A, S, Bn, C, ik);
      }
    }
  } else {
    const int SX = 1 << K;
#pragma unroll
    for (int s0 = 0; s0 < 8; ++s0) {
      if (s0 & SX) continue;
      const int s1 = s0 | SX;
      float4 as0 = g_AS[base + s0 * 64];
      float4 bc0 = g_BC[base + s0 * 64];
      v2f ik0 = g_IK[base + s0 * 64];
      float4 as1 = g_AS[base + s1 * 64];
      float4 bc1 = g_BC[base + s1 * 64];
      v2f ik1 = g_IK[base + s1 * 64];
      v2f A0, S0, Bn0, C0, A1, S1, Bn1, C1;
      A0.x = as0.x; A0.y = as0.y; S0.x = as0.z; S0.y = as0.w;
      Bn0.x = bc0.x; Bn0.y = bc0.y; C0.x = bc0.z; C0.y = bc0.w;
      A1.x = as1.x; A1.y = as1.y; S1.x = as1.z; S1.y = as1.w;
      Bn1.x = bc1.x; Bn1.y = bc1.y; C1.x = bc1.z; C1.y = bc1.w;
#pragma unroll
      for (int h = 0; h < RPW / 2; ++h) {
        v2f v0 = x[s0][h], v1 = x[s1][h];
        x[s0][h] = stepv(v0, v1, A0, S0, Bn0, C0, ik0);
        x[s1][h] = stepv(v1, v0, A1, S1, Bn1, C1, ik1);
      }
    }
  }
}

__global__ __launch_bounds__(256) void net_kernel(const float* __restrict__ X,
                                                  float* __restrict__ out) {
  const int lane = threadIdx.x & 63;
  const int wv = blockIdx.x * 4 + (threadIdx.x >> 6);
  const size_t row0 = (size_t)wv * RPW;

  // x[s][h] packs rows {2h, 2h+1} of physical position p = lane*8 + s
  v2f x[8][RPW / 2];
  const float4* __restrict__ Xv =
      reinterpret_cast<const float4*>(X + row0 * WIDTH);
#pragma unroll
  for (int r = 0; r < RPW; ++r) {
    float4 a = Xv[r * (WIDTH / 4) + lane * 2];
    float4 b = Xv[r * (WIDTH / 4) + lane * 2 + 1];
    float t[8] = {a.x, a.y, a.z, a.w, b.x, b.y, b.z, b.w};
#pragma unroll
    for (int s = 0; s < 8; ++s) {
      if (r & 1) x[s][r >> 1].y = t[s];
      else       x[s][r >> 1].x = t[s];
    }
  }

  // layer d pairs on physical bit k = 8 - (d % 9); pattern period 9
#define RUN_LAYER(DD)                       \
  do {                                      \
    if (d0 + DD < DEPTH) {                  \
      do_layer<8 - DD>(d0 + DD, lane, x);   \
    }                                       \
  } while (0)

  for (int d0 = 0; d0 < DEPTH; d0 += 9) {
    RUN_LAYER(0); RUN_LAYER(1); RUN_LAYER(2);
    RUN_LAYER(3); RUN_LAYER(4); RUN_LAYER(5);
    RUN_LAYER(6); RUN_LAYER(7); RUN_LAYER(8);
  }
#undef RUN_LAYER

  // final logical column of physical p is rotl9(p, 32 mod 9 = 5)
  float* __restrict__ O = out + row0 * WIDTH;
#pragma unroll
  for (int s = 0; s < 8; ++s) {
    const int p = lane * 8 + s;
    const int cfin = ((p << 5) | (p >> 4)) & 511;
#pragma unroll
    for (int h = 0; h < RPW / 2; ++h) {
      O[(2 * h) * WIDTH + cfin]     = x[s][h].x;
      O[(2 * h + 1) * WIDTH + cfin] = x[s][h].y;
    }
  }
}

extern "C" void kernel_launch(void* const* d_in, const int* in_sizes, int n_in,
                              void* d_out, int out_size, void* d_ws, size_t ws_size,
                              hipStream_t stream) {
  const float* X          = (const float*)d_in[0];
  const float* thetas     = (const float*)d_in[1];
  const float* biases     = (const float*)d_in[2];
  const float* slopes1    = (const float*)d_in[3];
  const float* slopes2    = (const float*)d_in[4];
  const float* curvatures = (const float*)d_in[5];
  float* out = (float*)d_out;

  hipLaunchKernelGGL(precompute_kernel, dim3((DEPTH * WIDTH + 255) / 256),
                     dim3(256), 0, stream, thetas, biases, slopes1, slopes2,
                     curvatures);
  hipLaunchKernelGGL(net_kernel, dim3(BATCH / (RPW * 4)), dim3(256), 0, stream,
                     X, out);
}

// Round 3
// 202.519 us; speedup vs baseline: 1.9493x; 1.9493x over previous
//
#include <hip/hip_runtime.h>
#include <math.h>

#define WIDTH 512
#define HALF  256
#define DEPTH 32
#define BATCH 65536
#define RPW   8   // rows per wave

// Precomputed per-(depth, physical position) parameters, stored in the
// physical order the main kernel reads them (coalesced):
//   entry index = d*512 + slot*64 + lane   for physical p = lane*8 + slot
// T1 = {A = a*cos(th), S = +-a*sin(th), B = sinh(bias), cc}
// T2 = invk = exp(-curv)
__device__ float4 g_T1[DEPTH * WIDTH];
__device__ float  g_T2[DEPTH * WIDTH];

__global__ __launch_bounds__(256) void precompute_kernel(
    const float* __restrict__ thetas, const float* __restrict__ biases,
    const float* __restrict__ slopes1, const float* __restrict__ slopes2,
    const float* __restrict__ curvatures) {
  int tid = blockIdx.x * 256 + threadIdx.x;
  if (tid >= DEPTH * WIDTH) return;
  int d = tid >> 9;
  int p = tid & 511;
  // logical column of physical p AFTER layer d = rotl9(p, d+1)
  int rot = (d + 1) % 9;
  int j = ((p << rot) | (p >> (9 - rot))) & 511;
  int i = j >> 1;          // theta index
  int role = j & 1;        // 0 = n0 (x0*c + x1*s), 1 = n1 (-x0*s + x1*c)
  float th = thetas[d * HALF + i];
  float c = cosf(th), s = sinf(th);
  float m1 = expf(slopes1[d * WIDTH + j]);
  float m2 = expf(slopes2[d * WIDTH + j]);
  float a  = 0.5f * (m1 + m2);
  float cc = (m2 - m1) / (m1 + m2);   // (m2-m1)/(2a)
  float b  = sinhf(biases[d * WIDTH + j]);
  float invk = expf(-curvatures[d * WIDTH + j]);
  float A = a * c;
  float S = role ? (-a * s) : (a * s);
  int q = d * WIDTH + ((p & 7) * 64 + (p >> 3));  // physical storage order
  g_T1[q] = make_float4(A, S, b, cc);
  g_T2[q] = invk;
}

#if __has_builtin(__builtin_amdgcn_sqrtf)
#define FAST_SQRT(x) __builtin_amdgcn_sqrtf(x)
#else
#define FAST_SQRT(x) sqrtf(x)
#endif

// xor-exchange across lanes. Masks 1..16 stay within 32-lane groups ->
// ds_swizzle BitMode (no address VGPR): offset = (xor<<10)|0x1F.
// Mask 32 crosses the 32-lane boundary -> __shfl_xor.
template <int M>
__device__ __forceinline__ float xshfl(float v) {
  if constexpr (M < 32) {
    constexpr int ctl = (M << 10) | 0x1F;
    return __int_as_float(__builtin_amdgcn_ds_swizzle(__float_as_int(v), ctl));
  } else {
    return __shfl_xor(v, 32, 64);
  }
}

__device__ __forceinline__ float stepf(float xs, float v, float4 P, float ik) {
  float u = fmaf(xs, P.x, fmaf(v, P.y, -P.z));
  float t = fmaf(u, u, ik);
  return fmaf(P.w, FAST_SQRT(t), u);
}

// K = physical bit index this layer pairs on.
// K >= 3: cross-lane (xor mask 1<<(K-3)); K < 3: intra-thread slot pair.
// t1/t2 are pre-offset to (d*512 + lane).
template <int K>
__device__ __forceinline__ void do_layer(const float4* __restrict__ t1,
                                         const float* __restrict__ t2,
                                         float (&x)[8][RPW]) {
  if constexpr (K >= 3) {
    constexpr int m = 1 << (K - 3);
#pragma unroll
    for (int s = 0; s < 8; ++s) {
      float4 P = t1[s * 64];
      float ik = t2[s * 64];
#pragma unroll
      for (int r = 0; r < RPW; ++r) {
        float xs = x[s][r];
        float v = xshfl<m>(xs);
        x[s][r] = stepf(xs, v, P, ik);
      }
    }
  } else {
    constexpr int SX = 1 << K;
#pragma unroll
    for (int s0 = 0; s0 < 8; ++s0) {
      if (s0 & SX) continue;
      const int s1 = s0 | SX;
      float4 P0 = t1[s0 * 64];
      float ik0 = t2[s0 * 64];
      float4 P1 = t1[s1 * 64];
      float ik1 = t2[s1 * 64];
#pragma unroll
      for (int r = 0; r < RPW; ++r) {
        float v0 = x[s0][r], v1 = x[s1][r];
        float n0 = stepf(v0, v1, P0, ik0);
        float n1 = stepf(v1, v0, P1, ik1);
        x[s0][r] = n0;
        x[s1][r] = n1;
      }
    }
  }
}

__global__ __launch_bounds__(256, 4) void net_kernel(const float* __restrict__ X,
                                                     float* __restrict__ out) {
  const int lane = threadIdx.x & 63;
  const int wv = blockIdx.x * 4 + (threadIdx.x >> 6);
  const size_t row0 = (size_t)wv * RPW;

  // physical position of x[s][r] within the row: p = lane*8 + s
  float x[8][RPW];
  const float4* __restrict__ Xv =
      reinterpret_cast<const float4*>(X + row0 * WIDTH);
#pragma unroll
  for (int r = 0; r < RPW; ++r) {
    float4 a = Xv[r * (WIDTH / 4) + lane * 2];
    float4 b = Xv[r * (WIDTH / 4) + lane * 2 + 1];
    x[0][r] = a.x; x[1][r] = a.y; x[2][r] = a.z; x[3][r] = a.w;
    x[4][r] = b.x; x[5][r] = b.y; x[6][r] = b.z; x[7][r] = b.w;
  }

  // layer d pairs on physical bit k = 8 - (d % 9); pattern period 9
#define RUN_LAYER(DD)                                                   \
  do {                                                                  \
    if (d0 + DD < DEPTH) {                                              \
      do_layer<8 - DD>(g_T1 + (d0 + DD) * WIDTH + lane,                 \
                       g_T2 + (d0 + DD) * WIDTH + lane, x);             \
    }                                                                   \
  } while (0)

  for (int d0 = 0; d0 < DEPTH; d0 += 9) {
    RUN_LAYER(0); RUN_LAYER(1); RUN_LAYER(2);
    RUN_LAYER(3); RUN_LAYER(4); RUN_LAYER(5);
    RUN_LAYER(6); RUN_LAYER(7); RUN_LAYER(8);
  }
#undef RUN_LAYER

  // final logical column of physical p is rotl9(p, 32 mod 9 = 5)
  float* __restrict__ O = out + row0 * WIDTH;
#pragma unroll
  for (int s = 0; s < 8; ++s) {
    const int p = lane * 8 + s;
    const int cfin = ((p << 5) | (p >> 4)) & 511;
#pragma unroll
    for (int r = 0; r < RPW; ++r) O[r * WIDTH + cfin] = x[s][r];
  }
}

extern "C" void kernel_launch(void* const* d_in, const int* in_sizes, int n_in,
                              void* d_out, int out_size, void* d_ws, size_t ws_size,
                              hipStream_t stream) {
  const float* X          = (const float*)d_in[0];
  const float* thetas     = (const float*)d_in[1];
  const float* biases     = (const float*)d_in[2];
  const float* slopes1    = (const float*)d_in[3];
  const float* slopes2    = (const float*)d_in[4];
  const float* curvatures = (const float*)d_in[5];
  float* out = (float*)d_out;

  hipLaunchKernelGGL(precompute_kernel, dim3((DEPTH * WIDTH + 255) / 256),
                     dim3(256), 0, stream, thetas, biases, slopes1, slopes2,
                     curvatures);
  hipLaunchKernelGGL(net_kernel, dim3(BATCH / (RPW * 4)), dim3(256), 0, stream,
                     X, out);
}